// Round 1
// baseline (547.830 us; speedup 1.0000x reference)
//
#include <hip/hip_runtime.h>
#include <cstdint>
#include <cstddef>

// Problem: out[n, r*256+c] = sum_{e,i} x[n, cell(r,e)*64+i] * v[e,i,r,c] + b[r*256+c]
// 49 independent (8192x192)@(192x256) GEMMs. bf16 MFMA, fp32 accumulate.

#define XCOLS   1728      // 27*64
#define ROWS_W  49
#define KTOT    192       // 3*64
#define OUTW    12544     // 49*256

typedef __attribute__((ext_vector_type(8))) short short8;
typedef __attribute__((ext_vector_type(4))) float f32x4;

struct CellTab { int c[ROWS_W][3]; };

// Faithful constexpr port of init_wincon_matrix(): cells[r][e] = board cell of
// the e-th put() for column r (step cycles 0,1,2 within each column).
constexpr CellTab make_cells() {
    CellTab t{};
    int step = 0, col = 0;
    int x = 0, y = 0, z = 0;
#define PUT() do { t.c[col][step] = x + 3*y + 9*z; step = (step + 1) % 3; } while (0)
    for (x = 0; x < 3; ++x) {
        for (y = 0; y < 3; ++y) {
            for (z = 0; z < 3; ++z) PUT();
            ++col;
        }
        for (z = 0; z < 3; ++z) {
            for (y = 0; y < 3; ++y) PUT();
            ++col;
        }
        for (y = 0; y < 3; ++y) { z = y; PUT(); }
        ++col;
        for (y = 0; y < 3; ++y) { z = 2 - y; PUT(); }
        ++col;
    }
    for (z = 0; z < 3; ++z) {
        for (y = 0; y < 3; ++y) {
            for (x = 0; x < 3; ++x) PUT();
            ++col;
        }
        for (y = 0; y < 3; ++y) { x = y; PUT(); }
        ++col;
        for (y = 0; y < 3; ++y) { x = 2 - y; PUT(); }
        ++col;
    }
    for (y = 0; y < 3; ++y) {
        for (z = 0; z < 3; ++z) { x = z; PUT(); }
        ++col;
        for (z = 0; z < 3; ++z) { x = 2 - z; PUT(); }
        ++col;
    }
    for (x = 0; x < 3; ++x) { y = x; z = x; PUT(); }
    ++col;
    for (x = 0; x < 3; ++x) { y = 2 - x; z = 2 - x; PUT(); }
    ++col;
    for (x = 0; x < 3; ++x) { y = x; z = 2 - x; PUT(); }
    ++col;
    for (x = 0; x < 3; ++x) { z = x; y = 2 - x; PUT(); }
    ++col;
#undef PUT
    return t;
}

__constant__ CellTab CELLS = make_cells();

__device__ __forceinline__ unsigned short f2bf(float f) {
    union { float f; unsigned u; } a; a.f = f;
    unsigned u = a.u;
    return (unsigned short)((u + 0x7fffu + ((u >> 16) & 1u)) >> 16);  // RNE
}

// ---------------------------------------------------------------------------
// Prepass: Wt[r][c][k] (bf16, k contiguous) = v[e][i][r][c], k = e*64+i.
// v flat index = (k*49 + r)*256 + c.  Reads coalesced over c; write 64B/thread.
// ---------------------------------------------------------------------------
__global__ __launch_bounds__(256) void wt_prepass(const float* __restrict__ v,
                                                  unsigned short* __restrict__ wt) {
    const int kq = blockIdx.x;   // 0..5  (k chunk of 32)
    const int r  = blockIdx.y;   // 0..48
    const int c  = threadIdx.x;  // 0..255
    const int k0 = kq * 32;
    unsigned short tmp[32];
#pragma unroll
    for (int kk = 0; kk < 32; ++kk) {
        const int k = k0 + kk;
        tmp[kk] = f2bf(v[(size_t)(k * 49 + r) * 256 + c]);
    }
    unsigned short* dst = wt + (size_t)(r * 256 + c) * KTOT + k0;
#pragma unroll
    for (int j = 0; j < 4; ++j) {
        short8 s;
#pragma unroll
        for (int i = 0; i < 8; ++i) s[i] = (short)tmp[j * 8 + i];
        *(short8*)(dst + j * 8) = s;
    }
}

// ---------------------------------------------------------------------------
// Main GEMM. Block = one (r, 128-row m-tile, 128-col n-tile). 256 thr / 4 waves.
// Wave w owns rows [w*32, w*32+32) x all 128 n. acc = 2 mt x 8 nt x f32x4.
// B chunk (32k x 128n) staged via global_load_lds into panel layout:
//   LDS 16B chunk idx (g*128 + n) holds Wt[r][cbase+n][kc*32 + g*8 .. +7]
// -> B-frag read for lane L, tile nt: chunk (L>>4)*128 + nt*16 + (L&15) : one
//    ds_read_b128, bank-balanced (8 lanes per 4-bank group = structural min).
// A read straight from global x (fp32) -> inline cvt -> bf16 frags; no LDS.
// ---------------------------------------------------------------------------
__global__ __launch_bounds__(256, 2) void tic_gemm(
    const float* __restrict__ x,
    const unsigned short* __restrict__ wt,
    const float* __restrict__ bias,
    float* __restrict__ out)
{
    const int bid   = blockIdx.x;
    const int r     = bid >> 7;        // same-r blocks consecutive -> L2 share
    const int sub   = bid & 127;
    const int mbase = (sub >> 1) * 128;
    const int cbase = (sub & 1) * 128;

    const int t    = threadIdx.x;
    const int wave = t >> 6;
    const int lane = t & 63;
    const int l15  = lane & 15;
    const int quad = lane >> 4;

    __shared__ __align__(16) unsigned short Bs[2][4096];  // 2 x 8 KB

    const int cell0 = CELLS.c[r][0];
    const int cell1 = CELLS.c[r][1];
    const int cell2 = CELLS.c[r][2];
    const int cells[3] = { cell0, cell1, cell2 };

    // acc init = bias (bias is per-column, same for all rows in a column)
    f32x4 acc[2][8];
#pragma unroll
    for (int nt = 0; nt < 8; ++nt) {
        const float bv = bias[r * 256 + cbase + nt * 16 + l15];
        f32x4 a; a[0] = bv; a[1] = bv; a[2] = bv; a[3] = bv;
        acc[0][nt] = a; acc[1][nt] = a;
    }

    auto stageB = [&](int kc, int buf) {
#pragma unroll
        for (int q = 0; q < 2; ++q) {
            const int cb = q * 256 + wave * 64;       // wave-uniform chunk base
            const int g  = cb >> 7;                   // uniform within wave
            const int n  = (cb & 127) + lane;         // per-lane
            const unsigned short* src =
                wt + (size_t)(r * 256 + cbase + n) * KTOT + kc * 32 + g * 8;
            unsigned short* dst = &Bs[buf][cb * 8];   // wave-uniform base
            __builtin_amdgcn_global_load_lds(
                (const __attribute__((address_space(1))) unsigned int*)src,
                (__attribute__((address_space(3))) unsigned int*)dst,
                16, 0, 0);
        }
    };

    float afp[2][2][8];  // [k-parity][mt][j]
    auto loadA = [&](int kc, int parity) {
        const int e = kc >> 1, h = kc & 1;
        const int colb = cells[e] * 64 + h * 32 + quad * 8;
#pragma unroll
        for (int mt = 0; mt < 2; ++mt) {
            const int row = mbase + wave * 32 + mt * 16 + l15;
            const float* p = x + (size_t)row * XCOLS + colb;
            const float4 a0 = *(const float4*)p;
            const float4 a1 = *(const float4*)(p + 4);
            afp[parity][mt][0] = a0.x; afp[parity][mt][1] = a0.y;
            afp[parity][mt][2] = a0.z; afp[parity][mt][3] = a0.w;
            afp[parity][mt][4] = a1.x; afp[parity][mt][5] = a1.y;
            afp[parity][mt][6] = a1.z; afp[parity][mt][7] = a1.w;
        }
    };

    loadA(0, 0);
    stageB(0, 0);
    __syncthreads();

#pragma unroll
    for (int kc = 0; kc < 6; ++kc) {
        const int buf = kc & 1;
        if (kc < 5) {
            stageB(kc + 1, buf ^ 1);
            loadA(kc + 1, (kc + 1) & 1);
        }
        short8 afr[2];
#pragma unroll
        for (int mt = 0; mt < 2; ++mt) {
            short8 a;
#pragma unroll
            for (int j = 0; j < 8; ++j) a[j] = (short)f2bf(afp[kc & 1][mt][j]);
            afr[mt] = a;
        }
#pragma unroll
        for (int nt = 0; nt < 8; ++nt) {
            const short8 bfr = *(const short8*)&Bs[buf][(quad * 128 + nt * 16 + l15) * 8];
            acc[0][nt] = __builtin_amdgcn_mfma_f32_16x16x32_bf16(afr[0], bfr, acc[0][nt], 0, 0, 0);
            acc[1][nt] = __builtin_amdgcn_mfma_f32_16x16x32_bf16(afr[1], bfr, acc[1][nt], 0, 0, 0);
        }
        __syncthreads();
    }

    // Epilogue: C/D layout col=lane&15, row=quad*4+reg  [m89-verified]
#pragma unroll
    for (int mt = 0; mt < 2; ++mt) {
#pragma unroll
        for (int v4 = 0; v4 < 4; ++v4) {
            const int row = mbase + wave * 32 + mt * 16 + quad * 4 + v4;
            float* orow = out + (size_t)row * OUTW + r * 256 + cbase;
#pragma unroll
            for (int nt = 0; nt < 8; ++nt)
                orow[nt * 16 + l15] = acc[mt][nt][v4];
        }
    }
}

extern "C" void kernel_launch(void* const* d_in, const int* in_sizes, int n_in,
                              void* d_out, int out_size, void* d_ws, size_t ws_size,
                              hipStream_t stream) {
    const float* x  = (const float*)d_in[0];   // (8192, 1728) fp32
    const float* v  = (const float*)d_in[1];   // (3, 64, 49, 256) fp32
    const float* b  = (const float*)d_in[2];   // (12544,) fp32
    float* out = (float*)d_out;                // (8192, 12544) fp32
    unsigned short* wt = (unsigned short*)d_ws; // Wt bf16: 49*256*192*2 = 4.8 MB

    wt_prepass<<<dim3(6, 49), dim3(256), 0, stream>>>(v, wt);
    tic_gemm<<<dim3(49 * 128), dim3(256), 0, stream>>>(x, wt, b, out);
}

// Round 2
// 534.973 us; speedup vs baseline: 1.0240x; 1.0240x over previous
//
#include <hip/hip_runtime.h>
#include <cstdint>
#include <cstddef>

// out[n, r*256+c] = sum_{e,i} x[n, cell(r,e)*64+i] * v[e,i,r,c] + b[r*256+c]
// 49 independent (8192x192)@(192x256) GEMMs. bf16 MFMA, fp32 accumulate.
// R2: x pre-cast to bf16 (kills per-block f2bf VALU), 256-col blocks (halves
// A traffic + block count), wave = 64rows x 128cols (4x A-reuse per B frag).

#define XCOLS   1728      // 27*64
#define ROWS_W  49
#define KTOT    192       // 3*64
#define OUTW    12544     // 49*256
#define XELEMS  (8192 * XCOLS)

typedef __attribute__((ext_vector_type(8))) short short8;
typedef __attribute__((ext_vector_type(4))) float f32x4;

struct CellTab { int c[ROWS_W][3]; };

// Faithful constexpr port of init_wincon_matrix(): cells[r][e] = board cell of
// the e-th put() for column r (step cycles 0,1,2 within each column).
constexpr CellTab make_cells() {
    CellTab t{};
    int step = 0, col = 0;
    int x = 0, y = 0, z = 0;
#define PUT() do { t.c[col][step] = x + 3*y + 9*z; step = (step + 1) % 3; } while (0)
    for (x = 0; x < 3; ++x) {
        for (y = 0; y < 3; ++y) {
            for (z = 0; z < 3; ++z) PUT();
            ++col;
        }
        for (z = 0; z < 3; ++z) {
            for (y = 0; y < 3; ++y) PUT();
            ++col;
        }
        for (y = 0; y < 3; ++y) { z = y; PUT(); }
        ++col;
        for (y = 0; y < 3; ++y) { z = 2 - y; PUT(); }
        ++col;
    }
    for (z = 0; z < 3; ++z) {
        for (y = 0; y < 3; ++y) {
            for (x = 0; x < 3; ++x) PUT();
            ++col;
        }
        for (y = 0; y < 3; ++y) { x = y; PUT(); }
        ++col;
        for (y = 0; y < 3; ++y) { x = 2 - y; PUT(); }
        ++col;
    }
    for (y = 0; y < 3; ++y) {
        for (z = 0; z < 3; ++z) { x = z; PUT(); }
        ++col;
        for (z = 0; z < 3; ++z) { x = 2 - z; PUT(); }
        ++col;
    }
    for (x = 0; x < 3; ++x) { y = x; z = x; PUT(); }
    ++col;
    for (x = 0; x < 3; ++x) { y = 2 - x; z = 2 - x; PUT(); }
    ++col;
    for (x = 0; x < 3; ++x) { y = x; z = 2 - x; PUT(); }
    ++col;
    for (x = 0; x < 3; ++x) { z = x; y = 2 - x; PUT(); }
    ++col;
#undef PUT
    return t;
}

__constant__ CellTab CELLS = make_cells();

__device__ __forceinline__ unsigned short f2bf(float f) {
    union { float f; unsigned u; } a; a.f = f;
    unsigned u = a.u;
    return (unsigned short)((u + 0x7fffu + ((u >> 16) & 1u)) >> 16);  // RNE
}

// ---------------------------------------------------------------------------
// Prepass A: xb[n][col] = bf16(x[n][col]), row-major. 8 elems/thread.
// ---------------------------------------------------------------------------
__global__ __launch_bounds__(256) void x_prepass(const float* __restrict__ x,
                                                 unsigned short* __restrict__ xb) {
    const size_t i8 = (size_t)(blockIdx.x * 256 + threadIdx.x) * 8;
    const float4 a0 = *(const float4*)(x + i8);
    const float4 a1 = *(const float4*)(x + i8 + 4);
    short8 s;
    s[0] = (short)f2bf(a0.x); s[1] = (short)f2bf(a0.y);
    s[2] = (short)f2bf(a0.z); s[3] = (short)f2bf(a0.w);
    s[4] = (short)f2bf(a1.x); s[5] = (short)f2bf(a1.y);
    s[6] = (short)f2bf(a1.z); s[7] = (short)f2bf(a1.w);
    *(short8*)(xb + i8) = s;
}

// ---------------------------------------------------------------------------
// Prepass B: Wt[r][c][k] (bf16, k contiguous) = v[e][i][r][c], k = e*64+i.
// ---------------------------------------------------------------------------
__global__ __launch_bounds__(256) void wt_prepass(const float* __restrict__ v,
                                                  unsigned short* __restrict__ wt) {
    const int kq = blockIdx.x;   // 0..5  (k chunk of 32)
    const int r  = blockIdx.y;   // 0..48
    const int c  = threadIdx.x;  // 0..255
    const int k0 = kq * 32;
    unsigned short tmp[32];
#pragma unroll
    for (int kk = 0; kk < 32; ++kk) {
        const int k = k0 + kk;
        tmp[kk] = f2bf(v[(size_t)(k * 49 + r) * 256 + c]);
    }
    unsigned short* dst = wt + (size_t)(r * 256 + c) * KTOT + k0;
#pragma unroll
    for (int j = 0; j < 4; ++j) {
        short8 s;
#pragma unroll
        for (int i = 0; i < 8; ++i) s[i] = (short)tmp[j * 8 + i];
        *(short8*)(dst + j * 8) = s;
    }
}

// ---------------------------------------------------------------------------
// Main GEMM. Block = one (r, 128-row m-tile) x ALL 256 cols. 256 thr / 4 waves.
// Wave (wh = wave>>1, half = wave&1) owns rows [wh*64, wh*64+64) x cols
// [half*128, half*128+128): acc = 4 mt x 8 nt x f32x4 = 128 VGPR.
// B chunk (32k x 256n) staged via global_load_lds, panel layout:
//   LDS 16B chunk (g*256 + n) = Wt[r][n][kc*32 + g*8 .. +7]
// B-frag (nt, lane): chunk quad*256 + half*128 + nt*16 + l15 -> ds_read_b128.
// A-frag: direct 16B short8 load from xb (already bf16) -> zero VALU cvt.
// Grid m-major (consecutive bids share m-tile -> x panel shared in L2/XCD).
// ---------------------------------------------------------------------------
__global__ __launch_bounds__(256, 2) void tic_gemm(
    const unsigned short* __restrict__ xb,
    const unsigned short* __restrict__ wt,
    const float* __restrict__ bias,
    float* __restrict__ out)
{
    const int bid   = blockIdx.x;
    const int m     = bid / 49;
    const int r     = bid % 49;
    const int mbase = m * 128;

    const int t    = threadIdx.x;
    const int wave = t >> 6;
    const int lane = t & 63;
    const int l15  = lane & 15;
    const int quad = lane >> 4;
    const int half = wave & 1;   // column half (0: cols 0-127, 1: 128-255)
    const int wh   = wave >> 1;  // row half (0: rows 0-63, 1: 64-127)

    __shared__ __align__(16) unsigned short Bs[2][8192];  // 2 x 16 KB

    const int cells[3] = { CELLS.c[r][0], CELLS.c[r][1], CELLS.c[r][2] };

    // acc init = bias (per-column, identical for all rows)
    f32x4 acc[4][8];
#pragma unroll
    for (int nt = 0; nt < 8; ++nt) {
        const float bv = bias[r * 256 + half * 128 + nt * 16 + l15];
        f32x4 a; a[0] = bv; a[1] = bv; a[2] = bv; a[3] = bv;
#pragma unroll
        for (int mt = 0; mt < 4; ++mt) acc[mt][nt] = a;
    }

    auto stageB = [&](int kc, int buf) {
#pragma unroll
        for (int q = 0; q < 4; ++q) {
            const int cb = q * 256 + wave * 64;       // wave-uniform chunk base
            const int n  = wave * 64 + lane;          // per-lane column
            const unsigned short* src =
                wt + (size_t)(r * 256 + n) * KTOT + kc * 32 + q * 8;
            unsigned short* dst = &Bs[buf][cb * 8];   // wave-uniform base
            __builtin_amdgcn_global_load_lds(
                (const __attribute__((address_space(1))) unsigned int*)src,
                (__attribute__((address_space(3))) unsigned int*)dst,
                16, 0, 0);
        }
    };

    short8 afr[2][4];  // [k-parity][mt] -- A frags straight from xb
    auto loadA = [&](int kc, int parity) {
        const int e = kc >> 1, h = kc & 1;
        const int colb = cells[e] * 64 + h * 32 + quad * 8;
#pragma unroll
        for (int mt = 0; mt < 4; ++mt) {
            const int row = mbase + wh * 64 + mt * 16 + l15;
            afr[parity][mt] = *(const short8*)(xb + (size_t)row * XCOLS + colb);
        }
    };

    loadA(0, 0);
    stageB(0, 0);
    __syncthreads();

#pragma unroll
    for (int kc = 0; kc < 6; ++kc) {
        const int buf = kc & 1;
        if (kc < 5) {
            stageB(kc + 1, buf ^ 1);
            loadA(kc + 1, (kc + 1) & 1);
        }
#pragma unroll
        for (int nt = 0; nt < 8; ++nt) {
            const short8 bfr = *(const short8*)
                &Bs[buf][(quad * 256 + half * 128 + nt * 16 + l15) * 8];
#pragma unroll
            for (int mt = 0; mt < 4; ++mt)
                acc[mt][nt] = __builtin_amdgcn_mfma_f32_16x16x32_bf16(
                    afr[kc & 1][mt], bfr, acc[mt][nt], 0, 0, 0);
        }
        __syncthreads();
    }

    // Epilogue: C/D layout col=lane&15, row=quad*4+reg  [m89-verified]
    // Each 16-lane group writes one aligned 64-B line per (mt,v4,nt).
#pragma unroll
    for (int mt = 0; mt < 4; ++mt) {
#pragma unroll
        for (int v4 = 0; v4 < 4; ++v4) {
            const int row = mbase + wh * 64 + mt * 16 + quad * 4 + v4;
            float* orow = out + (size_t)row * OUTW + r * 256 + half * 128;
#pragma unroll
            for (int nt = 0; nt < 8; ++nt)
                orow[nt * 16 + l15] = acc[mt][nt][v4];
        }
    }
}

extern "C" void kernel_launch(void* const* d_in, const int* in_sizes, int n_in,
                              void* d_out, int out_size, void* d_ws, size_t ws_size,
                              hipStream_t stream) {
    const float* x  = (const float*)d_in[0];   // (8192, 1728) fp32
    const float* v  = (const float*)d_in[1];   // (3, 64, 49, 256) fp32
    const float* b  = (const float*)d_in[2];   // (12544,) fp32
    float* out = (float*)d_out;                // (8192, 12544) fp32

    unsigned short* xb = (unsigned short*)d_ws;          // 28.3 MB bf16 x
    unsigned short* wt = xb + (size_t)XELEMS;            // 4.8 MB bf16 Wt

    x_prepass<<<dim3(XELEMS / (256 * 8)), dim3(256), 0, stream>>>(x, xb);
    wt_prepass<<<dim3(6, 49), dim3(256), 0, stream>>>(v, wt);
    tic_gemm<<<dim3(64 * 49), dim3(256), 0, stream>>>(xb, wt, b, out);
}